// Round 1
// baseline (311.266 us; speedup 1.0000x reference)
//
#include <hip/hip_runtime.h>

#define N_NODES 50000
#define E_EDGES 800000
#define D_IN 64
#define D_OUT 128

// Stage 2: scatter-add neighbor features into per-node sums.
// One thread per (edge, feature): gid = e*64 + f.
__global__ __launch_bounds__(256)
void scatter_kernel(const float* __restrict__ x,
                    const int* __restrict__ src,
                    const int* __restrict__ nbr,
                    float* __restrict__ sum,
                    float* __restrict__ cnt) {
    unsigned int gid = blockIdx.x * 256u + threadIdx.x;
    if (gid >= (unsigned int)E_EDGES * D_IN) return;
    int e = gid >> 6;   // /64
    int f = gid & 63;
    int s  = src[e];
    int nb = nbr[e];
    float v = x[nb * D_IN + f];
    atomicAdd(&sum[s * D_IN + f], v);
    if (f == 0) atomicAdd(&cnt[s], 1.0f);
}

// Stage 3: mean = (sum + x) / (cnt + 1)  (self loop folded in), out = mean @ W.
// Block = 256 threads handles 8 rows. W staged in LDS (32KB).
__global__ __launch_bounds__(256)
void mean_matmul_kernel(const float* __restrict__ sum,
                        const float* __restrict__ cnt,
                        const float* __restrict__ x,
                        const float* __restrict__ W,
                        float* __restrict__ out) {
    __shared__ float Wlds[D_IN * D_OUT];      // 32 KB
    __shared__ float mean_lds[8][D_IN];       // 2 KB
    const int tid = threadIdx.x;

    // Stage W into LDS, float4-vectorized: 2048 float4 / 256 threads = 8 each.
    const float4* W4  = (const float4*)W;
    float4*       Wl4 = (float4*)Wlds;
    #pragma unroll
    for (int i = tid; i < (D_IN * D_OUT) / 4; i += 256) Wl4[i] = W4[i];

    const int row0 = blockIdx.x * 8;

    // Compute 8 mean rows (512 values) into LDS: 2 per thread.
    for (int i = tid; i < 8 * D_IN; i += 256) {
        int r = i >> 6;
        int f = i & 63;
        int node = row0 + r;
        float m = 0.0f;
        if (node < N_NODES) {
            float c = cnt[node] + 1.0f;          // +1 for the self loop
            m = (sum[node * D_IN + f] + x[node * D_IN + f]) / c;
        }
        mean_lds[r][f] = m;
    }
    __syncthreads();

    // Each thread: one row, 4 consecutive cols (float4).
    const int r  = tid >> 5;          // 0..7
    const int cg = tid & 31;          // col group (4 cols each)
    const int node = row0 + r;

    float4 acc = {0.f, 0.f, 0.f, 0.f};
    const float4* Wrow4 = (const float4*)Wlds;
    #pragma unroll
    for (int k = 0; k < D_IN; ++k) {
        float  m = mean_lds[r][k];          // broadcast within 32-lane group
        float4 w = Wrow4[k * 32 + cg];      // ds_read_b128
        acc.x += m * w.x;
        acc.y += m * w.y;
        acc.z += m * w.z;
        acc.w += m * w.w;
    }
    if (node < N_NODES) {
        ((float4*)out)[node * 32 + cg] = acc;
    }
}

extern "C" void kernel_launch(void* const* d_in, const int* in_sizes, int n_in,
                              void* d_out, int out_size, void* d_ws, size_t ws_size,
                              hipStream_t stream) {
    const float* x  = (const float*)d_in[0];               // [N, 64]
    const int*   ei = (const int*)d_in[1];                 // [2, E] flat
    const float* W  = (const float*)d_in[2];               // [64, 128]
    float*       out = (float*)d_out;                      // [N, 128]

    const int* src = ei;                // edge_index[0] — segment ids
    const int* nbr = ei + E_EDGES;      // edge_index[1] — gather indices

    float* sum = (float*)d_ws;                         // N*64 floats = 12.8 MB
    float* cnt = sum + (size_t)N_NODES * D_IN;         // N floats   = 0.2 MB

    // Zero the accumulators (ws is poisoned 0xAA before every launch).
    size_t zero_bytes = ((size_t)N_NODES * D_IN + N_NODES) * sizeof(float);
    hipMemsetAsync(d_ws, 0, zero_bytes, stream);

    // Scatter: 800000 edges * 64 features = 51.2M threads.
    {
        unsigned int total = (unsigned int)E_EDGES * D_IN;
        unsigned int blocks = (total + 255u) / 256u;
        scatter_kernel<<<blocks, 256, 0, stream>>>(x, src, nbr, sum, cnt);
    }

    // Mean + GEMM: 8 rows per block.
    {
        unsigned int blocks = (N_NODES + 7) / 8;
        mean_matmul_kernel<<<blocks, 256, 0, stream>>>(sum, cnt, x, W, out);
    }
}